// Round 1
// 1293.702 us; speedup vs baseline: 1.0215x; 1.0215x over previous
//
#include <hip/hip_runtime.h>
#include <hip/hip_bf16.h>

using bf16 = __hip_bfloat16;
typedef __bf16 bfv8 __attribute__((ext_vector_type(8)));
typedef float f32x4 __attribute__((ext_vector_type(4)));

constexpr int B = 4, S = 4096, D = 1024, H = 16, DH = 64, WIN = 512, NW = S / WIN;
constexpr int M_ROWS = B * S;   // 16384
constexpr int FCH = 2048;       // FFN row chunk (hb = FCH*4096*2 = 16 MiB)
constexpr int NFCH = M_ROWS / FCH;
constexpr int QCH = 8192;       // QKV row chunk (srcb = QCH*1024*2 = 16 MiB)
constexpr int NQCH = M_ROWS / QCH;

#define DEV static __device__ __forceinline__

DEV float bf2f(bf16 x) { return __bfloat162float(x); }

DEV unsigned pack2bf(float a, float b) {
    union { __hip_bfloat162 h2; unsigned u; } cv;
    cv.h2.x = __float2bfloat16(a);
    cv.h2.y = __float2bfloat16(b);
    return cv.u;
}

DEV void store_val(float* p, float v) { *p = v; }
DEV void store_val(bf16* p, float v) { *p = __float2bfloat16(v); }

// async global->LDS, 16B per lane; LDS dest = wave-uniform base + lane*16
DEV void gload16(const bf16* g, bf16* l) {
    __builtin_amdgcn_global_load_lds(
        (const __attribute__((address_space(1))) unsigned int*)g,
        (__attribute__((address_space(3))) unsigned int*)l, 16, 0, 0);
}

// ---------------------------------------------------------------------------
// f32 -> bf16 bulk convert (8 elems/thread)
// ---------------------------------------------------------------------------
__global__ __launch_bounds__(256) void f2b_kernel(
    const float* __restrict__ in, bf16* __restrict__ out, int n8) {
    const int i = blockIdx.x * 256 + threadIdx.x;
    if (i >= n8) return;
    const float* p = in + (long)i * 8;
    const float4 a = *(const float4*)p;
    const float4 b = *(const float4*)(p + 4);
    uint4 pk;
    pk.x = pack2bf(a.x, a.y); pk.y = pack2bf(a.z, a.w);
    pk.z = pack2bf(b.x, b.y); pk.w = pack2bf(b.z, b.w);
    *(uint4*)(out + (long)i * 8) = pk;
}

// ---------------------------------------------------------------------------
// MFMA GEMM (m97 structure), unchanged (verified). QKV now uses bf16 A path
// (global_load_lds width-16) instead of the f32 VALU-pack staging path.
// ---------------------------------------------------------------------------
template <typename TA, typename TO, bool RELU, bool RESID, bool QKV,
          int WAVES_M, int WAVES_N, int WM, int WN>
__global__ __launch_bounds__(256) void mfma_gemm(
    const TA* __restrict__ A, const bf16* __restrict__ Wt,
    const float* __restrict__ bias, const bf16* __restrict__ resid,
    TO* __restrict__ out, int K, int N,
    TO* __restrict__ outk, TO* __restrict__ outv,
    const float* __restrict__ biask, const float* __restrict__ biasv) {
    constexpr int BM = WAVES_M * WM * 16;
    constexpr int BN = WAVES_N * WN * 16;
    constexpr int BK = 32;
    __shared__ bf16 As[BM][BK];
    __shared__ bf16 Bs[BN][BK];

    const int tid = threadIdx.x;
    const int wid = tid >> 6, lane = tid & 63;
    const int quad = lane >> 4, l16 = lane & 15;
    const int wm = (wid / WAVES_N) * (WM * 16);
    const int wn = (wid % WAVES_N) * (WN * 16);
    const long m0 = (long)blockIdx.y * BM;
    const long n0 = (long)blockIdx.x * BN;
    const int srow = tid >> 2;
    const int sk = (tid & 3) * 8;
    const int grow = wid * 16 + (lane >> 2);

    f32x4 acc[WM][WN] = {};

    for (int k0 = 0; k0 < K; k0 += BK) {
        __syncthreads();
        if constexpr (sizeof(TA) == 4) {
#pragma unroll
            for (int j = 0; j < BM / 64; ++j) {
                const float* ap = (const float*)A + (m0 + j * 64 + srow) * (long)K + k0 + sk;
                const float4 f0 = *(const float4*)ap;
                const float4 f1 = *(const float4*)(ap + 4);
                uint4 pk;
                pk.x = pack2bf(f0.x, f0.y); pk.y = pack2bf(f0.z, f0.w);
                pk.z = pack2bf(f1.x, f1.y); pk.w = pack2bf(f1.z, f1.w);
                *(uint4*)&As[j * 64 + srow][sk] = pk;
            }
        } else {
#pragma unroll
            for (int j = 0; j < BM / 64; ++j) {
                const bf16* ap = (const bf16*)A + (m0 + j * 64 + grow) * (long)K + k0 + (lane & 3) * 8;
                gload16(ap, (bf16*)((char*)&As[0][0] + j * 4096 + wid * 1024));
            }
        }
#pragma unroll
        for (int j = 0; j < BN / 64; ++j) {
            const bf16* bp = Wt + (n0 + j * 64 + grow) * (long)K + k0 + (lane & 3) * 8;
            gload16(bp, (bf16*)((char*)&Bs[0][0] + j * 4096 + wid * 1024));
        }
        __syncthreads();

        bfv8 af[WM], bfr[WN];
#pragma unroll
        for (int i = 0; i < WM; ++i)
            af[i] = *(const bfv8*)&As[wm + i * 16 + l16][quad * 8];
#pragma unroll
        for (int j = 0; j < WN; ++j)
            bfr[j] = *(const bfv8*)&Bs[wn + j * 16 + l16][quad * 8];
#pragma unroll
        for (int i = 0; i < WM; ++i)
#pragma unroll
            for (int j = 0; j < WN; ++j)
                acc[i][j] = __builtin_amdgcn_mfma_f32_16x16x32_bf16(af[i], bfr[j], acc[i][j], 0, 0, 0);
    }

#pragma unroll
    for (int i = 0; i < WM; ++i) {
#pragma unroll
        for (int r = 0; r < 4; ++r) {
            const long m = m0 + wm + i * 16 + quad * 4 + r;
#pragma unroll
            for (int j = 0; j < WN; ++j) {
                const long n = n0 + wn + j * 16 + l16;
                float val = acc[i][j][r];
                if constexpr (QKV) {
                    const int sel = (int)(n >> 10);
                    const long nn = n & 1023;
                    TO* op = sel == 0 ? out : (sel == 1 ? outk : outv);
                    const float* bp = sel == 0 ? bias : (sel == 1 ? biask : biasv);
                    store_val(op + m * 1024 + nn, val + bp[nn]);
                } else {
                    val += bias[n];
                    if constexpr (RELU) val = fmaxf(val, 0.f);
                    if constexpr (RESID) val += bf2f(resid[m * (long)N + n]);
                    store_val(out + m * (long)N + n, val);
                }
            }
        }
    }
}

// ---------------------------------------------------------------------------
// MFMA local causal attention. One wg per (b,h,64-query tile); 4 waves of 16
// queries each. Fixed-max softmax p = exp2(s*0.125*log2e - 16*log2e) (scores
// O(+-5): no over/underflow; same math as the verified scalar kernel).
// K staged [key][d] (QK^T B-frag = contiguous b128); V staged transposed
// [d][key] (PV B-frag = contiguous b128); P round-trips LDS per wave
// (C-layout -> A-layout, m120). Rows padded to 72 elems (144 B) -> <=2-way
// bank aliasing (free). Output (2*attn, bf16) overwrites Q in place; each
// wave touches only its own 16 rows x 64 head-cols -> race-free.
// ---------------------------------------------------------------------------
__global__ __launch_bounds__(256) void attn_mfma(
    bf16* __restrict__ q, const bf16* __restrict__ k,
    const bf16* __restrict__ v) {
    constexpr int LDK = 72;
    __shared__ bf16 Ks[64][LDK];
    __shared__ bf16 Vt[64][LDK];
    __shared__ bf16 Ps[4][16][LDK];

    const int tid = threadIdx.x;
    const int wid = tid >> 6, lane = tid & 63;
    const int quad = lane >> 4, l16 = lane & 15;
    const int qt = blockIdx.x & 63;
    const int bh = blockIdx.x >> 6;
    const int b_ = bh >> 4, h_ = bh & 15;
    const int qbase = qt * 64;
    const int wstart = qbase & ~(WIN - 1);
    const int kstart = (wstart == 0) ? 0 : wstart - WIN;
    const int ntiles = (qbase + 64 - kstart) >> 6;

    const long headoff = (long)h_ * DH;

    // Q A-frags: A[m=l16][k=quad*8+j], two k-chunks (0..31, 32..63)
    const bf16* qrow = q + ((long)b_ * S + qbase + wid * 16 + l16) * D + headoff + quad * 8;
    const bfv8 qa0 = *(const bfv8*)qrow;
    const bfv8 qa1 = *(const bfv8*)(qrow + 32);

    // staging index maps
    const int skey = tid >> 2;          // K: row 0..63
    const int sdp  = (tid & 3) * 16;    // K: 16-elem d group
    const int vkey = tid & 63;          // V: key (consecutive lanes -> no conflict)
    const int vdg  = tid >> 6;          // V: d group 0..3

    f32x4 o[4] = {};
    float lacc[4] = {};
    const int qp = qbase + wid * 16 + quad * 4;  // query pos of r=0

    for (int t = 0; t < ntiles; ++t) {
        const int kpos0 = kstart + t * 64;
        __syncthreads();  // prev iteration's LDS reads drained
        {
            const bf16* kp_ = k + ((long)b_ * S + kpos0 + skey) * D + headoff + sdp;
            const uint4 k0 = *(const uint4*)kp_;
            const uint4 k1 = *(const uint4*)(kp_ + 8);
            *(uint4*)&Ks[skey][sdp] = k0;
            *(uint4*)&Ks[skey][sdp + 8] = k1;
            const bf16* vp_ = v + ((long)b_ * S + kpos0 + vkey) * D + headoff + vdg * 16;
            bf16 vv[16];
            *(uint4*)&vv[0] = *(const uint4*)vp_;
            *(uint4*)&vv[8] = *(const uint4*)(vp_ + 8);
#pragma unroll
            for (int i = 0; i < 16; ++i) Vt[vdg * 16 + i][vkey] = vv[i];
        }
        __syncthreads();

        // S = Q K^T  (4 chunks of 16 keys), then p = exp2(fma(s)) masked
#pragma unroll
        for (int c = 0; c < 4; ++c) {
            const bfv8 kb0 = *(const bfv8*)&Ks[c * 16 + l16][quad * 8];
            const bfv8 kb1 = *(const bfv8*)&Ks[c * 16 + l16][quad * 8 + 32];
            f32x4 s = {};
            s = __builtin_amdgcn_mfma_f32_16x16x32_bf16(qa0, kb0, s, 0, 0, 0);
            s = __builtin_amdgcn_mfma_f32_16x16x32_bf16(qa1, kb1, s, 0, 0, 0);
            const int kp = kpos0 + c * 16 + l16;
#pragma unroll
            for (int r = 0; r < 4; ++r) {
                const float p = (kp <= qp + r)
                    ? exp2f(fmaf(s[r], 0.18033688f, -23.083120f)) : 0.f;
                lacc[r] += p;
                Ps[wid][quad * 4 + r][c * 16 + l16] = __float2bfloat16(p);
            }
        }

        // O += P V   (A from Ps round-trip, B from transposed Vt)
#pragma unroll
        for (int c2 = 0; c2 < 2; ++c2) {
            const bfv8 pa = *(const bfv8*)&Ps[wid][l16][c2 * 32 + quad * 8];
#pragma unroll
            for (int dc = 0; dc < 4; ++dc) {
                const bfv8 vb = *(const bfv8*)&Vt[dc * 16 + l16][c2 * 32 + quad * 8];
                o[dc] = __builtin_amdgcn_mfma_f32_16x16x32_bf16(pa, vb, o[dc], 0, 0, 0);
            }
        }
    }

    // reduce l across the 16-lane key-column group (masks 1,2,4,8 stay in-group)
#pragma unroll
    for (int r = 0; r < 4; ++r) {
#pragma unroll
        for (int m = 1; m < 16; m <<= 1) lacc[r] += __shfl_xor(lacc[r], m, 64);
    }
    float inv[4];
#pragma unroll
    for (int r = 0; r < 4; ++r) inv[r] = 2.f / lacc[r];  // x2 = "attn + attn"

    bf16* orow = q + ((long)b_ * S + qp) * D + headoff;
#pragma unroll
    for (int r = 0; r < 4; ++r)
#pragma unroll
        for (int dc = 0; dc < 4; ++dc)
            orow[(long)r * D + dc * 16 + l16] = __float2bfloat16(o[dc][r] * inv[r]);
}

// ---------------------------------------------------------------------------
// LayerNorm over last dim (1024), biased var, in-place safe.
// ---------------------------------------------------------------------------
template <typename TI, typename TO>
__global__ __launch_bounds__(256) void ln_kernel(
    const TI* in, const float* __restrict__ g, const float* __restrict__ be,
    TO* out) {
    __shared__ float red[4];
    const long row = blockIdx.x;
    const TI* x = in + row * D;
    const int tid = threadIdx.x;

    float v[4];
    float s = 0.f;
#pragma unroll
    for (int i = 0; i < 4; ++i) {
        v[i] = (float)x[tid + i * 256];
        s += v[i];
    }
#pragma unroll
    for (int off = 32; off; off >>= 1) s += __shfl_down(s, off, 64);
    if ((tid & 63) == 0) red[tid >> 6] = s;
    __syncthreads();
    const float mu = (red[0] + red[1] + red[2] + red[3]) * (1.f / D);
    __syncthreads();

    float vs = 0.f;
#pragma unroll
    for (int i = 0; i < 4; ++i) {
        const float d0 = v[i] - mu;
        vs += d0 * d0;
    }
#pragma unroll
    for (int off = 32; off; off >>= 1) vs += __shfl_down(vs, off, 64);
    if ((tid & 63) == 0) red[tid >> 6] = vs;
    __syncthreads();
    const float inv = rsqrtf((red[0] + red[1] + red[2] + red[3]) * (1.f / D) + 1e-5f);

#pragma unroll
    for (int i = 0; i < 4; ++i) {
        const int c = tid + i * 256;
        store_val(out + row * D + c, (v[i] - mu) * inv * g[c] + be[c]);
    }
}

// ---------------------------------------------------------------------------
extern "C" void kernel_launch(void* const* d_in, const int* in_sizes, int n_in,
                              void* d_out, int out_size, void* d_ws, size_t ws_size,
                              hipStream_t stream) {
    const float* src = (const float*)d_in[0];
    const float* wq = (const float*)d_in[1];  const float* bq = (const float*)d_in[2];
    const float* wk = (const float*)d_in[3];  const float* bk = (const float*)d_in[4];
    const float* wv = (const float*)d_in[5];  const float* bv = (const float*)d_in[6];
    const float* w1 = (const float*)d_in[7];  const float* b1 = (const float*)d_in[8];
    const float* w2 = (const float*)d_in[9];  const float* b2 = (const float*)d_in[10];
    const float* g1 = (const float*)d_in[11]; const float* be1 = (const float*)d_in[12];
    const float* g2 = (const float*)d_in[13]; const float* be2 = (const float*)d_in[14];

    // ws (64 MiB), phase 1 (QKV):  qb[0,32) | wqkvb[32,38) | srcb[40,56)
    // ws, phase 2 (FFN):           qb[0,32) | w1b[32,40) | w2b[40,48) | hb[48,64)
    //   (w1b/w2b converted AFTER the QKV GEMMs, overwriting wqkvb/srcb)
    // d_out (64 MiB f32): kb bf16 [0,32), vb bf16 [32,64) during attention;
    // then FFN2 writes f32 y over it chunk by chunk; LN2 in place.
    char* ws = (char*)d_ws;
    bf16* qb    = (bf16*)ws;
    bf16* wqkvb = (bf16*)(ws + (32L << 20));
    bf16* srcb  = (bf16*)(ws + (40L << 20));
    bf16* w1b   = (bf16*)(ws + (32L << 20));
    bf16* w2b   = (bf16*)(ws + (40L << 20));
    bf16* hb    = (bf16*)(ws + (48L << 20));
    bf16* kb    = (bf16*)d_out;
    bf16* vb    = (bf16*)d_out + (16L << 20);

    const dim3 blk(256);

    // QKV weights -> bf16
    f2b_kernel<<<dim3(512),  blk, 0, stream>>>(wq, wqkvb,            131072);
    f2b_kernel<<<dim3(512),  blk, 0, stream>>>(wk, wqkvb + (1L<<20), 131072);
    f2b_kernel<<<dim3(512),  blk, 0, stream>>>(wv, wqkvb + (2L<<20), 131072);

    // Fused QKV GEMM in 2 row-chunks: convert src chunk -> bf16, then
    // [8192,1024](bf16) x [3072,1024]^T via the global_load_lds A-path.
    for (int ch = 0; ch < NQCH; ++ch) {
        const long off = (long)ch * QCH * D;
        f2b_kernel<<<dim3(QCH * D / 8 / 256), blk, 0, stream>>>(
            src + off, srcb, QCH * D / 8);
        mfma_gemm<bf16, bf16, false, false, true, 2, 2, 4, 4>
            <<<dim3(3072 / 128, QCH / 128), blk, 0, stream>>>(
                srcb, wqkvb, bq, nullptr, qb + off, D, 3072,
                kb + off, vb + off, bk, bv);
    }

    // FFN weights -> bf16 (overwrites wqkvb/srcb regions, now dead)
    f2b_kernel<<<dim3(2048), blk, 0, stream>>>(w1, w1b, 524288);
    f2b_kernel<<<dim3(2048), blk, 0, stream>>>(w2, w2b, 524288);

    // MFMA local attention: x = 2*attn (bf16) over Q buffer
    attn_mfma<<<dim3(B * H * (S / 64)), blk, 0, stream>>>(qb, kb, vb);

    // LN1 in place
    ln_kernel<bf16, bf16><<<dim3(M_ROWS), blk, 0, stream>>>(qb, g1, be1, qb);

    // FFN chunks; gemm2 writes f32 y straight into d_out
    for (int ch = 0; ch < NFCH; ++ch) {
        const bf16* xc = qb + (long)ch * FCH * D;
        float* yc = (float*)d_out + (long)ch * FCH * D;
        mfma_gemm<bf16, bf16, true, false, false, 2, 2, 4, 4>
            <<<dim3(4096 / 128, FCH / 128), blk, 0, stream>>>(
                xc, w1b, b1, nullptr, hb, D, 4 * D, nullptr, nullptr, nullptr, nullptr);
        mfma_gemm<bf16, float, false, true, false, 4, 1, 2, 4>
            <<<dim3(1024 / 64, FCH / 128), blk, 0, stream>>>(
                hb, w2b, b2, xc, yc, 4 * D, D, nullptr, nullptr, nullptr, nullptr);
    }

    // LN2 in place on d_out (f32)
    ln_kernel<float, float><<<dim3(M_ROWS), blk, 0, stream>>>(
        (float*)d_out, g2, be2, (float*)d_out);
}

// Round 2
// 1072.347 us; speedup vs baseline: 1.2324x; 1.2064x over previous
//
#include <hip/hip_runtime.h>
#include <hip/hip_bf16.h>

using bf16 = __hip_bfloat16;
typedef __bf16 bfv8 __attribute__((ext_vector_type(8)));
typedef float f32x4 __attribute__((ext_vector_type(4)));

constexpr int B = 4, S = 4096, D = 1024, H = 16, DH = 64, WIN = 512, NW = S / WIN;
constexpr int M_ROWS = B * S;   // 16384
constexpr int FCH = 4096;       // FFN row chunk (hb = FCH*4096*2 = 32 MiB in d_out)
constexpr int NFCH = M_ROWS / FCH;
constexpr int QCH = 8192;       // QKV row chunk (srcb = QCH*1024*2 = 16 MiB)
constexpr int NQCH = M_ROWS / QCH;

#define DEV static __device__ __forceinline__

DEV float bf2f(bf16 x) { return __bfloat162float(x); }

DEV unsigned pack2bf(float a, float b) {
    union { __hip_bfloat162 h2; unsigned u; } cv;
    cv.h2.x = __float2bfloat16(a);
    cv.h2.y = __float2bfloat16(b);
    return cv.u;
}

DEV void store_val(float* p, float v) { *p = v; }
DEV void store_val(bf16* p, float v) { *p = __float2bfloat16(v); }

// async global->LDS, 16B per lane; LDS dest = wave-uniform base + lane*16
DEV void gload16(const bf16* g, bf16* l) {
    __builtin_amdgcn_global_load_lds(
        (const __attribute__((address_space(1))) unsigned int*)g,
        (__attribute__((address_space(3))) unsigned int*)l, 16, 0, 0);
}

// ---------------------------------------------------------------------------
// f32 -> bf16 bulk convert (8 elems/thread)
// ---------------------------------------------------------------------------
__global__ __launch_bounds__(256) void f2b_kernel(
    const float* __restrict__ in, bf16* __restrict__ out, int n8) {
    const int i = blockIdx.x * 256 + threadIdx.x;
    if (i >= n8) return;
    const float* p = in + (long)i * 8;
    const float4 a = *(const float4*)p;
    const float4 b = *(const float4*)(p + 4);
    uint4 pk;
    pk.x = pack2bf(a.x, a.y); pk.y = pack2bf(a.z, a.w);
    pk.z = pack2bf(b.x, b.y); pk.w = pack2bf(b.z, b.w);
    *(uint4*)(out + (long)i * 8) = pk;
}

// ---------------------------------------------------------------------------
// MFMA GEMM (m97 structure), unchanged (verified).
// ---------------------------------------------------------------------------
template <typename TA, typename TO, bool RELU, bool RESID, bool QKV,
          int WAVES_M, int WAVES_N, int WM, int WN>
__global__ __launch_bounds__(256) void mfma_gemm(
    const TA* __restrict__ A, const bf16* __restrict__ Wt,
    const float* __restrict__ bias, const bf16* __restrict__ resid,
    TO* __restrict__ out, int K, int N,
    TO* __restrict__ outk, TO* __restrict__ outv,
    const float* __restrict__ biask, const float* __restrict__ biasv) {
    constexpr int BM = WAVES_M * WM * 16;
    constexpr int BN = WAVES_N * WN * 16;
    constexpr int BK = 32;
    __shared__ bf16 As[BM][BK];
    __shared__ bf16 Bs[BN][BK];

    const int tid = threadIdx.x;
    const int wid = tid >> 6, lane = tid & 63;
    const int quad = lane >> 4, l16 = lane & 15;
    const int wm = (wid / WAVES_N) * (WM * 16);
    const int wn = (wid % WAVES_N) * (WN * 16);
    const long m0 = (long)blockIdx.y * BM;
    const long n0 = (long)blockIdx.x * BN;
    const int srow = tid >> 2;
    const int sk = (tid & 3) * 8;
    const int grow = wid * 16 + (lane >> 2);

    f32x4 acc[WM][WN] = {};

    for (int k0 = 0; k0 < K; k0 += BK) {
        __syncthreads();
        if constexpr (sizeof(TA) == 4) {
#pragma unroll
            for (int j = 0; j < BM / 64; ++j) {
                const float* ap = (const float*)A + (m0 + j * 64 + srow) * (long)K + k0 + sk;
                const float4 f0 = *(const float4*)ap;
                const float4 f1 = *(const float4*)(ap + 4);
                uint4 pk;
                pk.x = pack2bf(f0.x, f0.y); pk.y = pack2bf(f0.z, f0.w);
                pk.z = pack2bf(f1.x, f1.y); pk.w = pack2bf(f1.z, f1.w);
                *(uint4*)&As[j * 64 + srow][sk] = pk;
            }
        } else {
#pragma unroll
            for (int j = 0; j < BM / 64; ++j) {
                const bf16* ap = (const bf16*)A + (m0 + j * 64 + grow) * (long)K + k0 + (lane & 3) * 8;
                gload16(ap, (bf16*)((char*)&As[0][0] + j * 4096 + wid * 1024));
            }
        }
#pragma unroll
        for (int j = 0; j < BN / 64; ++j) {
            const bf16* bp = Wt + (n0 + j * 64 + grow) * (long)K + k0 + (lane & 3) * 8;
            gload16(bp, (bf16*)((char*)&Bs[0][0] + j * 4096 + wid * 1024));
        }
        __syncthreads();

        bfv8 af[WM], bfr[WN];
#pragma unroll
        for (int i = 0; i < WM; ++i)
            af[i] = *(const bfv8*)&As[wm + i * 16 + l16][quad * 8];
#pragma unroll
        for (int j = 0; j < WN; ++j)
            bfr[j] = *(const bfv8*)&Bs[wn + j * 16 + l16][quad * 8];
#pragma unroll
        for (int i = 0; i < WM; ++i)
#pragma unroll
            for (int j = 0; j < WN; ++j)
                acc[i][j] = __builtin_amdgcn_mfma_f32_16x16x32_bf16(af[i], bfr[j], acc[i][j], 0, 0, 0);
    }

#pragma unroll
    for (int i = 0; i < WM; ++i) {
#pragma unroll
        for (int r = 0; r < 4; ++r) {
            const long m = m0 + wm + i * 16 + quad * 4 + r;
#pragma unroll
            for (int j = 0; j < WN; ++j) {
                const long n = n0 + wn + j * 16 + l16;
                float val = acc[i][j][r];
                if constexpr (QKV) {
                    const int sel = (int)(n >> 10);
                    const long nn = n & 1023;
                    TO* op = sel == 0 ? out : (sel == 1 ? outk : outv);
                    const float* bp = sel == 0 ? bias : (sel == 1 ? biask : biasv);
                    store_val(op + m * 1024 + nn, val + bp[nn]);
                } else {
                    val += bias[n];
                    if constexpr (RELU) val = fmaxf(val, 0.f);
                    if constexpr (RESID) val += bf2f(resid[m * (long)N + n]);
                    store_val(out + m * (long)N + n, val);
                }
            }
        }
    }
}

// ---------------------------------------------------------------------------
// MFMA local causal attention (unchanged this round).
// ---------------------------------------------------------------------------
__global__ __launch_bounds__(256) void attn_mfma(
    bf16* __restrict__ q, const bf16* __restrict__ k,
    const bf16* __restrict__ v) {
    constexpr int LDK = 72;
    __shared__ bf16 Ks[64][LDK];
    __shared__ bf16 Vt[64][LDK];
    __shared__ bf16 Ps[4][16][LDK];

    const int tid = threadIdx.x;
    const int wid = tid >> 6, lane = tid & 63;
    const int quad = lane >> 4, l16 = lane & 15;
    const int qt = blockIdx.x & 63;
    const int bh = blockIdx.x >> 6;
    const int b_ = bh >> 4, h_ = bh & 15;
    const int qbase = qt * 64;
    const int wstart = qbase & ~(WIN - 1);
    const int kstart = (wstart == 0) ? 0 : wstart - WIN;
    const int ntiles = (qbase + 64 - kstart) >> 6;

    const long headoff = (long)h_ * DH;

    // Q A-frags: A[m=l16][k=quad*8+j], two k-chunks (0..31, 32..63)
    const bf16* qrow = q + ((long)b_ * S + qbase + wid * 16 + l16) * D + headoff + quad * 8;
    const bfv8 qa0 = *(const bfv8*)qrow;
    const bfv8 qa1 = *(const bfv8*)(qrow + 32);

    // staging index maps
    const int skey = tid >> 2;          // K: row 0..63
    const int sdp  = (tid & 3) * 16;    // K: 16-elem d group
    const int vkey = tid & 63;          // V: key (consecutive lanes -> no conflict)
    const int vdg  = tid >> 6;          // V: d group 0..3

    f32x4 o[4] = {};
    float lacc[4] = {};
    const int qp = qbase + wid * 16 + quad * 4;  // query pos of r=0

    for (int t = 0; t < ntiles; ++t) {
        const int kpos0 = kstart + t * 64;
        __syncthreads();  // prev iteration's LDS reads drained
        {
            const bf16* kp_ = k + ((long)b_ * S + kpos0 + skey) * D + headoff + sdp;
            const uint4 k0 = *(const uint4*)kp_;
            const uint4 k1 = *(const uint4*)(kp_ + 8);
            *(uint4*)&Ks[skey][sdp] = k0;
            *(uint4*)&Ks[skey][sdp + 8] = k1;
            const bf16* vp_ = v + ((long)b_ * S + kpos0 + vkey) * D + headoff + vdg * 16;
            bf16 vv[16];
            *(uint4*)&vv[0] = *(const uint4*)vp_;
            *(uint4*)&vv[8] = *(const uint4*)(vp_ + 8);
#pragma unroll
            for (int i = 0; i < 16; ++i) Vt[vdg * 16 + i][vkey] = vv[i];
        }
        __syncthreads();

        // S = Q K^T  (4 chunks of 16 keys), then p = exp2(fma(s)) masked
#pragma unroll
        for (int c = 0; c < 4; ++c) {
            const bfv8 kb0 = *(const bfv8*)&Ks[c * 16 + l16][quad * 8];
            const bfv8 kb1 = *(const bfv8*)&Ks[c * 16 + l16][quad * 8 + 32];
            f32x4 s = {};
            s = __builtin_amdgcn_mfma_f32_16x16x32_bf16(qa0, kb0, s, 0, 0, 0);
            s = __builtin_amdgcn_mfma_f32_16x16x32_bf16(qa1, kb1, s, 0, 0, 0);
            const int kp = kpos0 + c * 16 + l16;
#pragma unroll
            for (int r = 0; r < 4; ++r) {
                const float p = (kp <= qp + r)
                    ? exp2f(fmaf(s[r], 0.18033688f, -23.083120f)) : 0.f;
                lacc[r] += p;
                Ps[wid][quad * 4 + r][c * 16 + l16] = __float2bfloat16(p);
            }
        }

        // O += P V   (A from Ps round-trip, B from transposed Vt)
#pragma unroll
        for (int c2 = 0; c2 < 2; ++c2) {
            const bfv8 pa = *(const bfv8*)&Ps[wid][l16][c2 * 32 + quad * 8];
#pragma unroll
            for (int dc = 0; dc < 4; ++dc) {
                const bfv8 vb = *(const bfv8*)&Vt[dc * 16 + l16][c2 * 32 + quad * 8];
                o[dc] = __builtin_amdgcn_mfma_f32_16x16x32_bf16(pa, vb, o[dc], 0, 0, 0);
            }
        }
    }

    // reduce l across the 16-lane key-column group (masks 1,2,4,8 stay in-group)
#pragma unroll
    for (int r = 0; r < 4; ++r) {
#pragma unroll
        for (int m = 1; m < 16; m <<= 1) lacc[r] += __shfl_xor(lacc[r], m, 64);
    }
    float inv[4];
#pragma unroll
    for (int r = 0; r < 4; ++r) inv[r] = 2.f / lacc[r];  // x2 = "attn + attn"

    bf16* orow = q + ((long)b_ * S + qp) * D + headoff;
#pragma unroll
    for (int r = 0; r < 4; ++r)
#pragma unroll
        for (int dc = 0; dc < 4; ++dc)
            orow[(long)r * D + dc * 16 + l16] = __float2bfloat16(o[dc][r] * inv[r]);
}

// ---------------------------------------------------------------------------
// LayerNorm over last dim (1024), biased var, in-place safe.
// ADD=true: normalizes (in + in2) -- fused residual add.
// ---------------------------------------------------------------------------
template <typename TI, typename TO, bool ADD>
__global__ __launch_bounds__(256) void ln_kernel(
    const TI* in, const float* __restrict__ g, const float* __restrict__ be,
    TO* out, const TI* in2) {
    __shared__ float red[4];
    const long row = blockIdx.x;
    const TI* x = in + row * D;
    const TI* x2 = ADD ? in2 + row * D : nullptr;
    const int tid = threadIdx.x;

    float v[4];
    float s = 0.f;
#pragma unroll
    for (int i = 0; i < 4; ++i) {
        v[i] = (float)x[tid + i * 256];
        if constexpr (ADD) v[i] += (float)x2[tid + i * 256];
        s += v[i];
    }
#pragma unroll
    for (int off = 32; off; off >>= 1) s += __shfl_down(s, off, 64);
    if ((tid & 63) == 0) red[tid >> 6] = s;
    __syncthreads();
    const float mu = (red[0] + red[1] + red[2] + red[3]) * (1.f / D);
    __syncthreads();

    float vs = 0.f;
#pragma unroll
    for (int i = 0; i < 4; ++i) {
        const float d0 = v[i] - mu;
        vs += d0 * d0;
    }
#pragma unroll
    for (int off = 32; off; off >>= 1) vs += __shfl_down(vs, off, 64);
    if ((tid & 63) == 0) red[tid >> 6] = vs;
    __syncthreads();
    const float inv = rsqrtf((red[0] + red[1] + red[2] + red[3]) * (1.f / D) + 1e-5f);

#pragma unroll
    for (int i = 0; i < 4; ++i) {
        const int c = tid + i * 256;
        store_val(out + row * D + c, (v[i] - mu) * inv * g[c] + be[c]);
    }
}

// ---------------------------------------------------------------------------
extern "C" void kernel_launch(void* const* d_in, const int* in_sizes, int n_in,
                              void* d_out, int out_size, void* d_ws, size_t ws_size,
                              hipStream_t stream) {
    const float* src = (const float*)d_in[0];
    const float* wq = (const float*)d_in[1];  const float* bq = (const float*)d_in[2];
    const float* wk = (const float*)d_in[3];  const float* bk = (const float*)d_in[4];
    const float* wv = (const float*)d_in[5];  const float* bv = (const float*)d_in[6];
    const float* w1 = (const float*)d_in[7];  const float* b1 = (const float*)d_in[8];
    const float* w2 = (const float*)d_in[9];  const float* b2 = (const float*)d_in[10];
    const float* g1 = (const float*)d_in[11]; const float* be1 = (const float*)d_in[12];
    const float* g2 = (const float*)d_in[13]; const float* be2 = (const float*)d_in[14];

    // Buffer liveness plan:
    //  ws  (64 MiB): qb/x [0,32)  | phase1: wqkvb[32,38), srcb[40,56)
    //                             | phase2: fb (ffn bf16) [32,64)
    //  d_out (64 MiB): phase1: kb[0,32), vb[32,64)  (dead after attn)
    //                  phase2: w1b[0,8), w2b[8,16), hb[16,48)
    //                  finally: LN2 writes f32 y over all of d_out (all dead).
    char* ws = (char*)d_ws;
    bf16* qb    = (bf16*)ws;
    bf16* wqkvb = (bf16*)(ws + (32L << 20));
    bf16* srcb  = (bf16*)(ws + (40L << 20));
    bf16* fb    = (bf16*)(ws + (32L << 20));
    char* dob   = (char*)d_out;
    bf16* kb    = (bf16*)dob;
    bf16* vb    = (bf16*)(dob + (32L << 20));
    bf16* w1b   = (bf16*)dob;
    bf16* w2b   = (bf16*)(dob + (8L << 20));
    bf16* hb    = (bf16*)(dob + (16L << 20));

    const dim3 blk(256);

    // QKV weights -> bf16
    f2b_kernel<<<dim3(512),  blk, 0, stream>>>(wq, wqkvb,            131072);
    f2b_kernel<<<dim3(512),  blk, 0, stream>>>(wk, wqkvb + (1L<<20), 131072);
    f2b_kernel<<<dim3(512),  blk, 0, stream>>>(wv, wqkvb + (2L<<20), 131072);

    // Fused QKV GEMM in 2 row-chunks: convert src chunk -> bf16, then
    // [8192,1024](bf16) x [3072,1024]^T via the global_load_lds A-path.
    for (int ch = 0; ch < NQCH; ++ch) {
        const long off = (long)ch * QCH * D;
        f2b_kernel<<<dim3(QCH * D / 8 / 256), blk, 0, stream>>>(
            src + off, srcb, QCH * D / 8);
        mfma_gemm<bf16, bf16, false, false, true, 2, 2, 4, 4>
            <<<dim3(3072 / 128, QCH / 128), blk, 0, stream>>>(
                srcb, wqkvb, bq, nullptr, qb + off, D, 3072,
                kb + off, vb + off, bk, bv);
    }

    // MFMA local attention: x = 2*attn (bf16) over Q buffer
    attn_mfma<<<dim3(B * H * (S / 64)), blk, 0, stream>>>(qb, kb, vb);

    // FFN weights -> bf16 into d_out (kb/vb dead now)
    f2b_kernel<<<dim3(2048), blk, 0, stream>>>(w1, w1b, 524288);
    f2b_kernel<<<dim3(2048), blk, 0, stream>>>(w2, w2b, 524288);

    // LN1 in place on qb
    ln_kernel<bf16, bf16, false><<<dim3(M_ROWS), blk, 0, stream>>>(
        qb, g1, be1, qb, nullptr);

    // FFN in 4 chunks of 4096 rows; hb (32 MiB) in d_out; ffn out bf16 -> fb
    for (int ch = 0; ch < NFCH; ++ch) {
        const bf16* xc = qb + (long)ch * FCH * D;
        bf16* fc = fb + (long)ch * FCH * D;
        mfma_gemm<bf16, bf16, true, false, false, 2, 2, 4, 4>
            <<<dim3(4096 / 128, FCH / 128), blk, 0, stream>>>(
                xc, w1b, b1, nullptr, hb, D, 4 * D, nullptr, nullptr, nullptr, nullptr);
        mfma_gemm<bf16, bf16, false, false, false, 4, 1, 2, 4>
            <<<dim3(1024 / 64, FCH / 128), blk, 0, stream>>>(
                hb, w2b, b2, nullptr, fc, 4 * D, D, nullptr, nullptr, nullptr, nullptr);
    }

    // LN2: normalize (x + ffn), write f32 into d_out (contents all dead)
    ln_kernel<bf16, float, true><<<dim3(M_ROWS), blk, 0, stream>>>(
        qb, g2, be2, (float*)d_out, fb);
}

// Round 3
// 929.971 us; speedup vs baseline: 1.4211x; 1.1531x over previous
//
#include <hip/hip_runtime.h>
#include <hip/hip_bf16.h>

using bf16 = __hip_bfloat16;
typedef __bf16 bfv8 __attribute__((ext_vector_type(8)));
typedef float f32x4 __attribute__((ext_vector_type(4)));

constexpr int B = 4, S = 4096, D = 1024, H = 16, DH = 64, WIN = 512, NW = S / WIN;
constexpr int M_ROWS = B * S;   // 16384
constexpr int FCH = 8192;       // FFN row chunk (hb = FCH*4096*2 = 64 MiB in d_out)
constexpr int NFCH = M_ROWS / FCH;
constexpr int QCH = 8192;       // QKV row chunk (srcb = QCH*1024*2 = 16 MiB)
constexpr int NQCH = M_ROWS / QCH;

#define DEV static __device__ __forceinline__

DEV float bf2f(bf16 x) { return __bfloat162float(x); }

DEV unsigned pack2bf(float a, float b) {
    union { __hip_bfloat162 h2; unsigned u; } cv;
    cv.h2.x = __float2bfloat16(a);
    cv.h2.y = __float2bfloat16(b);
    return cv.u;
}

DEV void store_val(float* p, float v) { *p = v; }
DEV void store_val(bf16* p, float v) { *p = __float2bfloat16(v); }

// async global->LDS, 16B per lane; LDS dest = wave-uniform base + lane*16
DEV void gload16(const bf16* g, bf16* l) {
    __builtin_amdgcn_global_load_lds(
        (const __attribute__((address_space(1))) unsigned int*)g,
        (__attribute__((address_space(3))) unsigned int*)l, 16, 0, 0);
}

// ---------------------------------------------------------------------------
// f32 -> bf16 bulk convert (8 elems/thread)
// ---------------------------------------------------------------------------
__global__ __launch_bounds__(256) void f2b_kernel(
    const float* __restrict__ in, bf16* __restrict__ out, int n8) {
    const int i = blockIdx.x * 256 + threadIdx.x;
    if (i >= n8) return;
    const float* p = in + (long)i * 8;
    const float4 a = *(const float4*)p;
    const float4 b = *(const float4*)(p + 4);
    uint4 pk;
    pk.x = pack2bf(a.x, a.y); pk.y = pack2bf(a.z, a.w);
    pk.z = pack2bf(b.x, b.y); pk.w = pack2bf(b.z, b.w);
    *(uint4*)(out + (long)i * 8) = pk;
}

// ---------------------------------------------------------------------------
// MFMA GEMM (m97 structure), unchanged (verified).
// RESID=true reads resid at the output index and adds before store; safe for
// in-place resid==out (same thread reads then writes its own element).
// ---------------------------------------------------------------------------
template <typename TA, typename TO, bool RELU, bool RESID, bool QKV,
          int WAVES_M, int WAVES_N, int WM, int WN>
__global__ __launch_bounds__(256) void mfma_gemm(
    const TA* __restrict__ A, const bf16* __restrict__ Wt,
    const float* __restrict__ bias, const bf16* __restrict__ resid,
    TO* __restrict__ out, int K, int N,
    TO* __restrict__ outk, TO* __restrict__ outv,
    const float* __restrict__ biask, const float* __restrict__ biasv) {
    constexpr int BM = WAVES_M * WM * 16;
    constexpr int BN = WAVES_N * WN * 16;
    constexpr int BK = 32;
    __shared__ bf16 As[BM][BK];
    __shared__ bf16 Bs[BN][BK];

    const int tid = threadIdx.x;
    const int wid = tid >> 6, lane = tid & 63;
    const int quad = lane >> 4, l16 = lane & 15;
    const int wm = (wid / WAVES_N) * (WM * 16);
    const int wn = (wid % WAVES_N) * (WN * 16);
    const long m0 = (long)blockIdx.y * BM;
    const long n0 = (long)blockIdx.x * BN;
    const int srow = tid >> 2;
    const int sk = (tid & 3) * 8;
    const int grow = wid * 16 + (lane >> 2);

    f32x4 acc[WM][WN] = {};

    for (int k0 = 0; k0 < K; k0 += BK) {
        __syncthreads();
        if constexpr (sizeof(TA) == 4) {
#pragma unroll
            for (int j = 0; j < BM / 64; ++j) {
                const float* ap = (const float*)A + (m0 + j * 64 + srow) * (long)K + k0 + sk;
                const float4 f0 = *(const float4*)ap;
                const float4 f1 = *(const float4*)(ap + 4);
                uint4 pk;
                pk.x = pack2bf(f0.x, f0.y); pk.y = pack2bf(f0.z, f0.w);
                pk.z = pack2bf(f1.x, f1.y); pk.w = pack2bf(f1.z, f1.w);
                *(uint4*)&As[j * 64 + srow][sk] = pk;
            }
        } else {
#pragma unroll
            for (int j = 0; j < BM / 64; ++j) {
                const bf16* ap = (const bf16*)A + (m0 + j * 64 + grow) * (long)K + k0 + (lane & 3) * 8;
                gload16(ap, (bf16*)((char*)&As[0][0] + j * 4096 + wid * 1024));
            }
        }
#pragma unroll
        for (int j = 0; j < BN / 64; ++j) {
            const bf16* bp = Wt + (n0 + j * 64 + grow) * (long)K + k0 + (lane & 3) * 8;
            gload16(bp, (bf16*)((char*)&Bs[0][0] + j * 4096 + wid * 1024));
        }
        __syncthreads();

        bfv8 af[WM], bfr[WN];
#pragma unroll
        for (int i = 0; i < WM; ++i)
            af[i] = *(const bfv8*)&As[wm + i * 16 + l16][quad * 8];
#pragma unroll
        for (int j = 0; j < WN; ++j)
            bfr[j] = *(const bfv8*)&Bs[wn + j * 16 + l16][quad * 8];
#pragma unroll
        for (int i = 0; i < WM; ++i)
#pragma unroll
            for (int j = 0; j < WN; ++j)
                acc[i][j] = __builtin_amdgcn_mfma_f32_16x16x32_bf16(af[i], bfr[j], acc[i][j], 0, 0, 0);
    }

#pragma unroll
    for (int i = 0; i < WM; ++i) {
#pragma unroll
        for (int r = 0; r < 4; ++r) {
            const long m = m0 + wm + i * 16 + quad * 4 + r;
#pragma unroll
            for (int j = 0; j < WN; ++j) {
                const long n = n0 + wn + j * 16 + l16;
                float val = acc[i][j][r];
                if constexpr (QKV) {
                    const int sel = (int)(n >> 10);
                    const long nn = n & 1023;
                    TO* op = sel == 0 ? out : (sel == 1 ? outk : outv);
                    const float* bp = sel == 0 ? bias : (sel == 1 ? biask : biasv);
                    store_val(op + m * 1024 + nn, val + bp[nn]);
                } else {
                    val += bias[n];
                    if constexpr (RELU) val = fmaxf(val, 0.f);
                    if constexpr (RESID) val += bf2f(resid[m * (long)N + n]);
                    store_val(out + m * (long)N + n, val);
                }
            }
        }
    }
}

// ---------------------------------------------------------------------------
// MFMA local causal attention (unchanged this round).
// ---------------------------------------------------------------------------
__global__ __launch_bounds__(256) void attn_mfma(
    bf16* __restrict__ q, const bf16* __restrict__ k,
    const bf16* __restrict__ v) {
    constexpr int LDK = 72;
    __shared__ bf16 Ks[64][LDK];
    __shared__ bf16 Vt[64][LDK];
    __shared__ bf16 Ps[4][16][LDK];

    const int tid = threadIdx.x;
    const int wid = tid >> 6, lane = tid & 63;
    const int quad = lane >> 4, l16 = lane & 15;
    const int qt = blockIdx.x & 63;
    const int bh = blockIdx.x >> 6;
    const int b_ = bh >> 4, h_ = bh & 15;
    const int qbase = qt * 64;
    const int wstart = qbase & ~(WIN - 1);
    const int kstart = (wstart == 0) ? 0 : wstart - WIN;
    const int ntiles = (qbase + 64 - kstart) >> 6;

    const long headoff = (long)h_ * DH;

    // Q A-frags: A[m=l16][k=quad*8+j], two k-chunks (0..31, 32..63)
    const bf16* qrow = q + ((long)b_ * S + qbase + wid * 16 + l16) * D + headoff + quad * 8;
    const bfv8 qa0 = *(const bfv8*)qrow;
    const bfv8 qa1 = *(const bfv8*)(qrow + 32);

    // staging index maps
    const int skey = tid >> 2;          // K: row 0..63
    const int sdp  = (tid & 3) * 16;    // K: 16-elem d group
    const int vkey = tid & 63;          // V: key (consecutive lanes -> no conflict)
    const int vdg  = tid >> 6;          // V: d group 0..3

    f32x4 o[4] = {};
    float lacc[4] = {};
    const int qp = qbase + wid * 16 + quad * 4;  // query pos of r=0

    for (int t = 0; t < ntiles; ++t) {
        const int kpos0 = kstart + t * 64;
        __syncthreads();  // prev iteration's LDS reads drained
        {
            const bf16* kp_ = k + ((long)b_ * S + kpos0 + skey) * D + headoff + sdp;
            const uint4 k0 = *(const uint4*)kp_;
            const uint4 k1 = *(const uint4*)(kp_ + 8);
            *(uint4*)&Ks[skey][sdp] = k0;
            *(uint4*)&Ks[skey][sdp + 8] = k1;
            const bf16* vp_ = v + ((long)b_ * S + kpos0 + vkey) * D + headoff + vdg * 16;
            bf16 vv[16];
            *(uint4*)&vv[0] = *(const uint4*)vp_;
            *(uint4*)&vv[8] = *(const uint4*)(vp_ + 8);
#pragma unroll
            for (int i = 0; i < 16; ++i) Vt[vdg * 16 + i][vkey] = vv[i];
        }
        __syncthreads();

        // S = Q K^T  (4 chunks of 16 keys), then p = exp2(fma(s)) masked
#pragma unroll
        for (int c = 0; c < 4; ++c) {
            const bfv8 kb0 = *(const bfv8*)&Ks[c * 16 + l16][quad * 8];
            const bfv8 kb1 = *(const bfv8*)&Ks[c * 16 + l16][quad * 8 + 32];
            f32x4 s = {};
            s = __builtin_amdgcn_mfma_f32_16x16x32_bf16(qa0, kb0, s, 0, 0, 0);
            s = __builtin_amdgcn_mfma_f32_16x16x32_bf16(qa1, kb1, s, 0, 0, 0);
            const int kp = kpos0 + c * 16 + l16;
#pragma unroll
            for (int r = 0; r < 4; ++r) {
                const float p = (kp <= qp + r)
                    ? exp2f(fmaf(s[r], 0.18033688f, -23.083120f)) : 0.f;
                lacc[r] += p;
                Ps[wid][quad * 4 + r][c * 16 + l16] = __float2bfloat16(p);
            }
        }

        // O += P V   (A from Ps round-trip, B from transposed Vt)
#pragma unroll
        for (int c2 = 0; c2 < 2; ++c2) {
            const bfv8 pa = *(const bfv8*)&Ps[wid][l16][c2 * 32 + quad * 8];
#pragma unroll
            for (int dc = 0; dc < 4; ++dc) {
                const bfv8 vb = *(const bfv8*)&Vt[dc * 16 + l16][c2 * 32 + quad * 8];
                o[dc] = __builtin_amdgcn_mfma_f32_16x16x32_bf16(pa, vb, o[dc], 0, 0, 0);
            }
        }
    }

    // reduce l across the 16-lane key-column group (masks 1,2,4,8 stay in-group)
#pragma unroll
    for (int r = 0; r < 4; ++r) {
#pragma unroll
        for (int m = 1; m < 16; m <<= 1) lacc[r] += __shfl_xor(lacc[r], m, 64);
    }
    float inv[4];
#pragma unroll
    for (int r = 0; r < 4; ++r) inv[r] = 2.f / lacc[r];  // x2 = "attn + attn"

    bf16* orow = q + ((long)b_ * S + qp) * D + headoff;
#pragma unroll
    for (int r = 0; r < 4; ++r)
#pragma unroll
        for (int dc = 0; dc < 4; ++dc)
            orow[(long)r * D + dc * 16 + l16] = __float2bfloat16(o[dc][r] * inv[r]);
}

// ---------------------------------------------------------------------------
// LayerNorm over last dim (1024), biased var, in-place safe.
// ADD=true: normalizes (in + in2) -- fused residual add.
// ---------------------------------------------------------------------------
template <typename TI, typename TO, bool ADD>
__global__ __launch_bounds__(256) void ln_kernel(
    const TI* in, const float* __restrict__ g, const float* __restrict__ be,
    TO* out, const TI* in2) {
    __shared__ float red[4];
    const long row = blockIdx.x;
    const TI* x = in + row * D;
    const TI* x2 = ADD ? in2 + row * D : nullptr;
    const int tid = threadIdx.x;

    float v[4];
    float s = 0.f;
#pragma unroll
    for (int i = 0; i < 4; ++i) {
        v[i] = (float)x[tid + i * 256];
        if constexpr (ADD) v[i] += (float)x2[tid + i * 256];
        s += v[i];
    }
#pragma unroll
    for (int off = 32; off; off >>= 1) s += __shfl_down(s, off, 64);
    if ((tid & 63) == 0) red[tid >> 6] = s;
    __syncthreads();
    const float mu = (red[0] + red[1] + red[2] + red[3]) * (1.f / D);
    __syncthreads();

    float vs = 0.f;
#pragma unroll
    for (int i = 0; i < 4; ++i) {
        const float d0 = v[i] - mu;
        vs += d0 * d0;
    }
#pragma unroll
    for (int off = 32; off; off >>= 1) vs += __shfl_down(vs, off, 64);
    if ((tid & 63) == 0) red[tid >> 6] = vs;
    __syncthreads();
    const float inv = rsqrtf((red[0] + red[1] + red[2] + red[3]) * (1.f / D) + 1e-5f);

#pragma unroll
    for (int i = 0; i < 4; ++i) {
        const int c = tid + i * 256;
        store_val(out + row * D + c, (v[i] - mu) * inv * g[c] + be[c]);
    }
}

// ---------------------------------------------------------------------------
extern "C" void kernel_launch(void* const* d_in, const int* in_sizes, int n_in,
                              void* d_out, int out_size, void* d_ws, size_t ws_size,
                              hipStream_t stream) {
    const float* src = (const float*)d_in[0];
    const float* wq = (const float*)d_in[1];  const float* bq = (const float*)d_in[2];
    const float* wk = (const float*)d_in[3];  const float* bk = (const float*)d_in[4];
    const float* wv = (const float*)d_in[5];  const float* bv = (const float*)d_in[6];
    const float* w1 = (const float*)d_in[7];  const float* b1 = (const float*)d_in[8];
    const float* w2 = (const float*)d_in[9];  const float* b2 = (const float*)d_in[10];
    const float* g1 = (const float*)d_in[11]; const float* be1 = (const float*)d_in[12];
    const float* g2 = (const float*)d_in[13]; const float* be2 = (const float*)d_in[14];

    // Buffer liveness plan:
    //  ws  (64 MiB): qb/x/z [0,32) | phase1: wqkvb[32,38), srcb[40,56)
    //                              | phase2: w1b[32,40), w2b[40,48)
    //  d_out (64 MiB): phase1: kb[0,32), vb[32,64)  (dead after attn)
    //                  phase2: hb[0,64)  (full 8192x4096 bf16 h chunk)
    //                  finally: LN2 writes f32 y over all of d_out (hb dead).
    //  gemm2 fuses resid-add and writes z = x+ffn bf16 IN-PLACE over qb
    //  (each element read-as-resid + written by the same thread).
    char* ws = (char*)d_ws;
    bf16* qb    = (bf16*)ws;
    bf16* wqkvb = (bf16*)(ws + (32L << 20));
    bf16* srcb  = (bf16*)(ws + (40L << 20));
    bf16* w1b   = (bf16*)(ws + (32L << 20));
    bf16* w2b   = (bf16*)(ws + (40L << 20));
    char* dob   = (char*)d_out;
    bf16* kb    = (bf16*)dob;
    bf16* vb    = (bf16*)(dob + (32L << 20));
    bf16* hb    = (bf16*)dob;

    const dim3 blk(256);

    // QKV weights -> bf16
    f2b_kernel<<<dim3(512),  blk, 0, stream>>>(wq, wqkvb,            131072);
    f2b_kernel<<<dim3(512),  blk, 0, stream>>>(wk, wqkvb + (1L<<20), 131072);
    f2b_kernel<<<dim3(512),  blk, 0, stream>>>(wv, wqkvb + (2L<<20), 131072);

    // Fused QKV GEMM in 2 row-chunks: convert src chunk -> bf16, then
    // [8192,1024](bf16) x [3072,1024]^T via the global_load_lds A-path.
    for (int ch = 0; ch < NQCH; ++ch) {
        const long off = (long)ch * QCH * D;
        f2b_kernel<<<dim3(QCH * D / 8 / 256), blk, 0, stream>>>(
            src + off, srcb, QCH * D / 8);
        mfma_gemm<bf16, bf16, false, false, true, 2, 2, 4, 4>
            <<<dim3(3072 / 128, QCH / 128), blk, 0, stream>>>(
                srcb, wqkvb, bq, nullptr, qb + off, D, 3072,
                kb + off, vb + off, bk, bv);
    }

    // FFN weights -> bf16 into ws[32,48) (wqkvb/srcb dead after QKV gemms)
    f2b_kernel<<<dim3(2048), blk, 0, stream>>>(w1, w1b, 524288);
    f2b_kernel<<<dim3(2048), blk, 0, stream>>>(w2, w2b, 524288);

    // MFMA local attention: x = 2*attn (bf16) over Q buffer
    attn_mfma<<<dim3(B * H * (S / 64)), blk, 0, stream>>>(qb, kb, vb);

    // LN1 in place on qb
    ln_kernel<bf16, bf16, false><<<dim3(M_ROWS), blk, 0, stream>>>(
        qb, g1, be1, qb, nullptr);

    // FFN in 2 chunks of 8192 rows; hb = all of d_out (kb/vb dead).
    // gemm1: 2048 wg (8/CU); gemm2: 1024 wg (4/CU), z = x+ffn in-place on qb.
    for (int ch = 0; ch < NFCH; ++ch) {
        bf16* xc = qb + (long)ch * FCH * D;
        mfma_gemm<bf16, bf16, true, false, false, 2, 2, 4, 4>
            <<<dim3(4096 / 128, FCH / 128), blk, 0, stream>>>(
                xc, w1b, b1, nullptr, hb, D, 4 * D, nullptr, nullptr, nullptr, nullptr);
        mfma_gemm<bf16, bf16, false, true, false, 4, 1, 2, 4>
            <<<dim3(1024 / 64, FCH / 128), blk, 0, stream>>>(
                hb, w2b, b2, xc, xc, 4 * D, D, nullptr, nullptr, nullptr, nullptr);
    }

    // LN2 on z (bf16, in qb), write f32 into d_out (hb dead)
    ln_kernel<bf16, float, false><<<dim3(M_ROWS), blk, 0, stream>>>(
        qb, g2, be2, (float*)d_out, nullptr);
}

// Round 5
// 896.903 us; speedup vs baseline: 1.4735x; 1.0369x over previous
//
#include <hip/hip_runtime.h>
#include <hip/hip_bf16.h>

using bf16 = __hip_bfloat16;
typedef __bf16 bfv8 __attribute__((ext_vector_type(8)));
typedef float f32x4 __attribute__((ext_vector_type(4)));

constexpr int B = 4, S = 4096, D = 1024, H = 16, DH = 64, WIN = 512, NW = S / WIN;
constexpr int M_ROWS = B * S;   // 16384
constexpr int FCH = 8192;       // FFN row chunk (hb = FCH*4096*2 = 64 MiB in d_out)
constexpr int NFCH = M_ROWS / FCH;
constexpr int QCH = 8192;       // QKV row chunk (srcb = QCH*1024*2 = 16 MiB)
constexpr int NQCH = M_ROWS / QCH;

#define DEV static __device__ __forceinline__

DEV float bf2f(bf16 x) { return __bfloat162float(x); }

DEV unsigned pack2bf(float a, float b) {
    union { __hip_bfloat162 h2; unsigned u; } cv;
    cv.h2.x = __float2bfloat16(a);
    cv.h2.y = __float2bfloat16(b);
    return cv.u;
}

DEV void store_val(float* p, float v) { *p = v; }
DEV void store_val(bf16* p, float v) { *p = __float2bfloat16(v); }

// async global->LDS, 16B per lane; LDS dest = wave-uniform base + lane*16
DEV void gload16(const bf16* g, bf16* l) {
    __builtin_amdgcn_global_load_lds(
        (const __attribute__((address_space(1))) unsigned int*)g,
        (__attribute__((address_space(3))) unsigned int*)l, 16, 0, 0);
}

// ---------------------------------------------------------------------------
// f32 -> bf16 bulk convert (8 elems/thread)
// ---------------------------------------------------------------------------
__global__ __launch_bounds__(256) void f2b_kernel(
    const float* __restrict__ in, bf16* __restrict__ out, int n8) {
    const int i = blockIdx.x * 256 + threadIdx.x;
    if (i >= n8) return;
    const float* p = in + (long)i * 8;
    const float4 a = *(const float4*)p;
    const float4 b = *(const float4*)(p + 4);
    uint4 pk;
    pk.x = pack2bf(a.x, a.y); pk.y = pack2bf(a.z, a.w);
    pk.z = pack2bf(b.x, b.y); pk.w = pack2bf(b.z, b.w);
    *(uint4*)(out + (long)i * 8) = pk;
}

// ---------------------------------------------------------------------------
// MFMA GEMM (m97 structure; verified). T1 XCD-chunked blockIdx swizzle
// (grid sizes all %8==0 -> bijective) so each XCD's private L2 sees a
// contiguous panel range (A row-panels stop being re-fetched by all 8 XCDs).
// RESID=true reads resid at the output index and adds before store; safe for
// in-place resid==out (same thread reads then writes its own element).
// ---------------------------------------------------------------------------
template <typename TA, typename TO, bool RELU, bool RESID, bool QKV,
          int WAVES_M, int WAVES_N, int WM, int WN>
__global__ __launch_bounds__(256) void mfma_gemm(
    const TA* __restrict__ A, const bf16* __restrict__ Wt,
    const float* __restrict__ bias, const bf16* __restrict__ resid,
    TO* __restrict__ out, int K, int N,
    TO* __restrict__ outk, TO* __restrict__ outv,
    const float* __restrict__ biask, const float* __restrict__ biasv) {
    constexpr int BM = WAVES_M * WM * 16;
    constexpr int BN = WAVES_N * WN * 16;
    constexpr int BK = 32;
    __shared__ bf16 As[BM][BK];
    __shared__ bf16 Bs[BN][BK];

    const int tid = threadIdx.x;
    const int wid = tid >> 6, lane = tid & 63;
    const int quad = lane >> 4, l16 = lane & 15;
    const int wm = (wid / WAVES_N) * (WM * 16);
    const int wn = (wid % WAVES_N) * (WN * 16);

    // XCD-chunked swizzle (T1): orig%8 = XCD -> give each XCD a contiguous
    // chunk of the flattened grid.
    const int nwg = gridDim.x * gridDim.y;
    const int orig = blockIdx.y * gridDim.x + blockIdx.x;
    const int chunk = nwg >> 3;
    const int swz = (orig & 7) * chunk + (orig >> 3);
    const int bx = swz % gridDim.x;
    const int by = swz / gridDim.x;

    const long m0 = (long)by * BM;
    const long n0 = (long)bx * BN;
    const int srow = tid >> 2;
    const int sk = (tid & 3) * 8;
    const int grow = wid * 16 + (lane >> 2);

    f32x4 acc[WM][WN] = {};

    for (int k0 = 0; k0 < K; k0 += BK) {
        __syncthreads();
        if constexpr (sizeof(TA) == 4) {
#pragma unroll
            for (int j = 0; j < BM / 64; ++j) {
                const float* ap = (const float*)A + (m0 + j * 64 + srow) * (long)K + k0 + sk;
                const float4 f0 = *(const float4*)ap;
                const float4 f1 = *(const float4*)(ap + 4);
                uint4 pk;
                pk.x = pack2bf(f0.x, f0.y); pk.y = pack2bf(f0.z, f0.w);
                pk.z = pack2bf(f1.x, f1.y); pk.w = pack2bf(f1.z, f1.w);
                *(uint4*)&As[j * 64 + srow][sk] = pk;
            }
        } else {
#pragma unroll
            for (int j = 0; j < BM / 64; ++j) {
                const bf16* ap = (const bf16*)A + (m0 + j * 64 + grow) * (long)K + k0 + (lane & 3) * 8;
                gload16(ap, (bf16*)((char*)&As[0][0] + j * 4096 + wid * 1024));
            }
        }
#pragma unroll
        for (int j = 0; j < BN / 64; ++j) {
            const bf16* bp = Wt + (n0 + j * 64 + grow) * (long)K + k0 + (lane & 3) * 8;
            gload16(bp, (bf16*)((char*)&Bs[0][0] + j * 4096 + wid * 1024));
        }
        __syncthreads();

        bfv8 af[WM], bfr[WN];
#pragma unroll
        for (int i = 0; i < WM; ++i)
            af[i] = *(const bfv8*)&As[wm + i * 16 + l16][quad * 8];
#pragma unroll
        for (int j = 0; j < WN; ++j)
            bfr[j] = *(const bfv8*)&Bs[wn + j * 16 + l16][quad * 8];
#pragma unroll
        for (int i = 0; i < WM; ++i)
#pragma unroll
            for (int j = 0; j < WN; ++j)
                acc[i][j] = __builtin_amdgcn_mfma_f32_16x16x32_bf16(af[i], bfr[j], acc[i][j], 0, 0, 0);
    }

#pragma unroll
    for (int i = 0; i < WM; ++i) {
#pragma unroll
        for (int r = 0; r < 4; ++r) {
            const long m = m0 + wm + i * 16 + quad * 4 + r;
#pragma unroll
            for (int j = 0; j < WN; ++j) {
                const long n = n0 + wn + j * 16 + l16;
                float val = acc[i][j][r];
                if constexpr (QKV) {
                    const int sel = (int)(n >> 10);
                    const long nn = n & 1023;
                    TO* op = sel == 0 ? out : (sel == 1 ? outk : outv);
                    const float* bp = sel == 0 ? bias : (sel == 1 ? biask : biasv);
                    store_val(op + m * 1024 + nn, val + bp[nn]);
                } else {
                    val += bias[n];
                    if constexpr (RELU) val = fmaxf(val, 0.f);
                    if constexpr (RESID) val += bf2f(resid[m * (long)N + n]);
                    store_val(out + m * (long)N + n, val);
                }
            }
        }
    }
}

// ---------------------------------------------------------------------------
// MFMA local causal attention, v2: QBLK=128 (8 waves of 16 queries, 512 thr)
// + T14 async-stage (prefetch next K/V tile into registers during compute).
// Staging per query halves vs QBLK=64; global-load latency hides under
// QK/softmax/PV. Math identical to the verified v1: fixed-max softmax
// p = exp2(fma(s, 0.125*log2e, -16*log2e)); K staged [key][d]; V staged
// transposed [d][key]; P round-trips LDS per wave (C->A layout); rows padded
// to 72 elems. Output (2*attn, bf16) overwrites Q in place; each wave owns
// its 16 rows x 64 head-cols -> race-free. Waves whose queries are entirely
// below a key tile see fully-masked p=0 -> correct, minor wasted MFMA.
// ---------------------------------------------------------------------------
__global__ __launch_bounds__(512) void attn_mfma(
    bf16* __restrict__ q, const bf16* __restrict__ k,
    const bf16* __restrict__ v) {
    constexpr int LDK = 72;
    __shared__ bf16 Ks[64][LDK];
    __shared__ bf16 Vt[64][LDK];
    __shared__ bf16 Ps[8][16][LDK];

    const int tid = threadIdx.x;
    const int wid = tid >> 6, lane = tid & 63;
    const int quad = lane >> 4, l16 = lane & 15;
    const int qt = blockIdx.x & 31;          // S/128 = 32 query tiles
    const int bh = blockIdx.x >> 5;
    const int b_ = bh >> 4, h_ = bh & 15;
    const int qbase = qt * 128;
    const int wstart = qbase & ~(WIN - 1);
    const int kstart = (wstart == 0) ? 0 : wstart - WIN;
    const int ntiles = (qbase + 128 - kstart) >> 6;

    const long headoff = (long)h_ * DH;

    // Q A-frags: A[m=l16][k=quad*8+j], two k-chunks (0..31, 32..63)
    const bf16* qrow = q + ((long)b_ * S + qbase + wid * 16 + l16) * D + headoff + quad * 8;
    const bfv8 qa0 = *(const bfv8*)qrow;
    const bfv8 qa1 = *(const bfv8*)(qrow + 32);

    // staging index maps (512 threads)
    const int skey = tid >> 3;          // K: row 0..63, 8 thr/row
    const int sdp  = (tid & 7) * 8;     // K: 8-elem d group
    const int vkey = tid & 63;          // V: key (lane) -> conflict-free writes
    const int vdg  = tid >> 6;          // V: d group 0..7 (= wid)

    const bf16* kbase = k + (long)b_ * S * D + headoff;
    const bf16* vbase = v + (long)b_ * S * D + headoff;

    f32x4 o[4] = {};
    float lacc[4] = {};
    const int qp = qbase + wid * 16 + quad * 4;  // query pos of r=0

    // prefetch tile 0
    uint4 kreg = *(const uint4*)(kbase + (long)(kstart + skey) * D + sdp);
    uint4 vreg = *(const uint4*)(vbase + (long)(kstart + vkey) * D + vdg * 8);

    for (int t = 0; t < ntiles; ++t) {
        // write staged tile t to LDS (vmcnt wait inserted by compiler)
        *(uint4*)&Ks[skey][sdp] = kreg;
        {
            bf16 vv[8];
            *(uint4*)&vv[0] = vreg;
#pragma unroll
            for (int i = 0; i < 8; ++i) Vt[vdg * 8 + i][vkey] = vv[i];
        }
        __syncthreads();

        // prefetch tile t+1 (in flight across the whole compute phase)
        if (t + 1 < ntiles) {
            const int kn = kstart + (t + 1) * 64;
            kreg = *(const uint4*)(kbase + (long)(kn + skey) * D + sdp);
            vreg = *(const uint4*)(vbase + (long)(kn + vkey) * D + vdg * 8);
        }

        const int kpos0 = kstart + t * 64;

        // S = Q K^T  (4 chunks of 16 keys), then p = exp2(fma(s)) masked
#pragma unroll
        for (int c = 0; c < 4; ++c) {
            const bfv8 kb0 = *(const bfv8*)&Ks[c * 16 + l16][quad * 8];
            const bfv8 kb1 = *(const bfv8*)&Ks[c * 16 + l16][quad * 8 + 32];
            f32x4 s = {};
            s = __builtin_amdgcn_mfma_f32_16x16x32_bf16(qa0, kb0, s, 0, 0, 0);
            s = __builtin_amdgcn_mfma_f32_16x16x32_bf16(qa1, kb1, s, 0, 0, 0);
            const int kp = kpos0 + c * 16 + l16;
#pragma unroll
            for (int r = 0; r < 4; ++r) {
                const float p = (kp <= qp + r)
                    ? exp2f(fmaf(s[r], 0.18033688f, -23.083120f)) : 0.f;
                lacc[r] += p;
                Ps[wid][quad * 4 + r][c * 16 + l16] = __float2bfloat16(p);
            }
        }

        // O += P V   (A from Ps round-trip, B from transposed Vt)
#pragma unroll
        for (int c2 = 0; c2 < 2; ++c2) {
            const bfv8 pa = *(const bfv8*)&Ps[wid][l16][c2 * 32 + quad * 8];
#pragma unroll
            for (int dc = 0; dc < 4; ++dc) {
                const bfv8 vb = *(const bfv8*)&Vt[dc * 16 + l16][c2 * 32 + quad * 8];
                o[dc] = __builtin_amdgcn_mfma_f32_16x16x32_bf16(pa, vb, o[dc], 0, 0, 0);
            }
        }
        __syncthreads();  // all waves done reading before next writes
    }

    // reduce l across the 16-lane key-column group (masks 1,2,4,8 stay in-group)
#pragma unroll
    for (int r = 0; r < 4; ++r) {
#pragma unroll
        for (int m = 1; m < 16; m <<= 1) lacc[r] += __shfl_xor(lacc[r], m, 64);
    }
    float inv[4];
#pragma unroll
    for (int r = 0; r < 4; ++r) inv[r] = 2.f / lacc[r];  // x2 = "attn + attn"

    bf16* orow = q + ((long)b_ * S + qp) * D + headoff;
#pragma unroll
    for (int r = 0; r < 4; ++r)
#pragma unroll
        for (int dc = 0; dc < 4; ++dc)
            orow[(long)r * D + dc * 16 + l16] = __float2bfloat16(o[dc][r] * inv[r]);
}

// ---------------------------------------------------------------------------
// LayerNorm over last dim (1024), biased var, in-place safe.
// ADD=true: normalizes (in + in2) -- fused residual add.
// ---------------------------------------------------------------------------
template <typename TI, typename TO, bool ADD>
__global__ __launch_bounds__(256) void ln_kernel(
    const TI* in, const float* __restrict__ g, const float* __restrict__ be,
    TO* out, const TI* in2) {
    __shared__ float red[4];
    const long row = blockIdx.x;
    const TI* x = in + row * D;
    const TI* x2 = ADD ? in2 + row * D : nullptr;
    const int tid = threadIdx.x;

    float v[4];
    float s = 0.f;
#pragma unroll
    for (int i = 0; i < 4; ++i) {
        v[i] = (float)x[tid + i * 256];
        if constexpr (ADD) v[i] += (float)x2[tid + i * 256];
        s += v[i];
    }
#pragma unroll
    for (int off = 32; off; off >>= 1) s += __shfl_down(s, off, 64);
    if ((tid & 63) == 0) red[tid >> 6] = s;
    __syncthreads();
    const float mu = (red[0] + red[1] + red[2] + red[3]) * (1.f / D);
    __syncthreads();

    float vs = 0.f;
#pragma unroll
    for (int i = 0; i < 4; ++i) {
        const float d0 = v[i] - mu;
        vs += d0 * d0;
    }
#pragma unroll
    for (int off = 32; off; off >>= 1) vs += __shfl_down(vs, off, 64);
    if ((tid & 63) == 0) red[tid >> 6] = vs;
    __syncthreads();
    const float inv = rsqrtf((red[0] + red[1] + red[2] + red[3]) * (1.f / D) + 1e-5f);

#pragma unroll
    for (int i = 0; i < 4; ++i) {
        const int c = tid + i * 256;
        store_val(out + row * D + c, (v[i] - mu) * inv * g[c] + be[c]);
    }
}

// ---------------------------------------------------------------------------
extern "C" void kernel_launch(void* const* d_in, const int* in_sizes, int n_in,
                              void* d_out, int out_size, void* d_ws, size_t ws_size,
                              hipStream_t stream) {
    const float* src = (const float*)d_in[0];
    const float* wq = (const float*)d_in[1];  const float* bq = (const float*)d_in[2];
    const float* wk = (const float*)d_in[3];  const float* bk = (const float*)d_in[4];
    const float* wv = (const float*)d_in[5];  const float* bv = (const float*)d_in[6];
    const float* w1 = (const float*)d_in[7];  const float* b1 = (const float*)d_in[8];
    const float* w2 = (const float*)d_in[9];  const float* b2 = (const float*)d_in[10];
    const float* g1 = (const float*)d_in[11]; const float* be1 = (const float*)d_in[12];
    const float* g2 = (const float*)d_in[13]; const float* be2 = (const float*)d_in[14];

    // Buffer liveness plan:
    //  ws  (64 MiB): qb/x/z [0,32) | phase1: wqkvb[32,38), srcb[40,56)
    //                              | phase2: w1b[32,40), w2b[40,48)
    //  d_out (64 MiB): phase1: kb[0,32), vb[32,64)  (dead after attn)
    //                  phase2: hb[0,64)  (full 8192x4096 bf16 h chunk)
    //                  finally: LN2 writes f32 y over all of d_out (hb dead).
    //  gemm2 fuses resid-add and writes z = x+ffn bf16 IN-PLACE over qb
    //  (each element read-as-resid + written by the same thread).
    char* ws = (char*)d_ws;
    bf16* qb    = (bf16*)ws;
    bf16* wqkvb = (bf16*)(ws + (32L << 20));
    bf16* srcb  = (bf16*)(ws + (40L << 20));
    bf16* w1b   = (bf16*)(ws + (32L << 20));
    bf16* w2b   = (bf16*)(ws + (40L << 20));
    char* dob   = (char*)d_out;
    bf16* kb    = (bf16*)dob;
    bf16* vb    = (bf16*)(dob + (32L << 20));
    bf16* hb    = (bf16*)dob;

    const dim3 blk(256);

    // QKV weights -> bf16
    f2b_kernel<<<dim3(512),  blk, 0, stream>>>(wq, wqkvb,            131072);
    f2b_kernel<<<dim3(512),  blk, 0, stream>>>(wk, wqkvb + (1L<<20), 131072);
    f2b_kernel<<<dim3(512),  blk, 0, stream>>>(wv, wqkvb + (2L<<20), 131072);

    // Fused QKV GEMM in 2 row-chunks: convert src chunk -> bf16, then
    // [8192,1024](bf16) x [3072,1024]^T via the global_load_lds A-path.
    for (int ch = 0; ch < NQCH; ++ch) {
        const long off = (long)ch * QCH * D;
        f2b_kernel<<<dim3(QCH * D / 8 / 256), blk, 0, stream>>>(
            src + off, srcb, QCH * D / 8);
        mfma_gemm<bf16, bf16, false, false, true, 2, 2, 4, 4>
            <<<dim3(3072 / 128, QCH / 128), blk, 0, stream>>>(
                srcb, wqkvb, bq, nullptr, qb + off, D, 3072,
                kb + off, vb + off, bk, bv);
    }

    // FFN weights -> bf16 into ws[32,48) (wqkvb/srcb dead after QKV gemms)
    f2b_kernel<<<dim3(2048), blk, 0, stream>>>(w1, w1b, 524288);
    f2b_kernel<<<dim3(2048), blk, 0, stream>>>(w2, w2b, 524288);

    // MFMA local attention: x = 2*attn (bf16) over Q buffer (512-thr wgs)
    attn_mfma<<<dim3(B * H * (S / 128)), dim3(512), 0, stream>>>(qb, kb, vb);

    // LN1 in place on qb
    ln_kernel<bf16, bf16, false><<<dim3(M_ROWS), blk, 0, stream>>>(
        qb, g1, be1, qb, nullptr);

    // FFN in 2 chunks of 8192 rows; hb = all of d_out (kb/vb dead).
    // gemm1: 2048 wg (8/CU); gemm2: 1024 wg (4/CU), z = x+ffn in-place on qb.
    for (int ch = 0; ch < NFCH; ++ch) {
        bf16* xc = qb + (long)ch * FCH * D;
        mfma_gemm<bf16, bf16, true, false, false, 2, 2, 4, 4>
            <<<dim3(4096 / 128, FCH / 128), blk, 0, stream>>>(
                xc, w1b, b1, nullptr, hb, D, 4 * D, nullptr, nullptr, nullptr, nullptr);
        mfma_gemm<bf16, bf16, false, true, false, 4, 1, 2, 4>
            <<<dim3(1024 / 64, FCH / 128), blk, 0, stream>>>(
                hb, w2b, b2, xc, xc, 4 * D, D, nullptr, nullptr, nullptr, nullptr);
    }

    // LN2 on z (bf16, in qb), write f32 into d_out (hb dead)
    ln_kernel<bf16, float, false><<<dim3(M_ROWS), blk, 0, stream>>>(
        qb, g2, be2, (float*)d_out, nullptr);
}

// Round 6
// 789.723 us; speedup vs baseline: 1.6734x; 1.1357x over previous
//
#include <hip/hip_runtime.h>
#include <hip/hip_bf16.h>

using bf16 = __hip_bfloat16;
typedef __bf16 bfv8 __attribute__((ext_vector_type(8)));
typedef float f32x4 __attribute__((ext_vector_type(4)));

constexpr int B = 4, S = 4096, D = 1024, H = 16, DH = 64, WIN = 512, NW = S / WIN;
constexpr int M_ROWS = B * S;   // 16384
constexpr int FCH = 8192;       // FFN row chunk (hb = FCH*4096*2 = 64 MiB in d_out)
constexpr int NFCH = M_ROWS / FCH;
constexpr int QCH = 8192;       // QKV row chunk (srcb = QCH*1024*2 = 16 MiB)
constexpr int NQCH = M_ROWS / QCH;

#define DEV static __device__ __forceinline__

DEV float bf2f(bf16 x) { return __bfloat162float(x); }

DEV unsigned pack2bf(float a, float b) {
    union { __hip_bfloat162 h2; unsigned u; } cv;
    cv.h2.x = __float2bfloat16(a);
    cv.h2.y = __float2bfloat16(b);
    return cv.u;
}

DEV void store_val(float* p, float v) { *p = v; }
DEV void store_val(bf16* p, float v) { *p = __float2bfloat16(v); }

// async global->LDS, 16B per lane; LDS dest = wave-uniform base + lane*16
DEV void gload16(const bf16* g, bf16* l) {
    __builtin_amdgcn_global_load_lds(
        (const __attribute__((address_space(1))) unsigned int*)g,
        (__attribute__((address_space(3))) unsigned int*)l, 16, 0, 0);
}

// ---------------------------------------------------------------------------
// f32 -> bf16 bulk convert (8 elems/thread)
// ---------------------------------------------------------------------------
__global__ __launch_bounds__(256) void f2b_kernel(
    const float* __restrict__ in, bf16* __restrict__ out, int n8) {
    const int i = blockIdx.x * 256 + threadIdx.x;
    if (i >= n8) return;
    const float* p = in + (long)i * 8;
    const float4 a = *(const float4*)p;
    const float4 b = *(const float4*)(p + 4);
    uint4 pk;
    pk.x = pack2bf(a.x, a.y); pk.y = pack2bf(a.z, a.w);
    pk.z = pack2bf(b.x, b.y); pk.w = pack2bf(b.z, b.w);
    *(uint4*)(out + (long)i * 8) = pk;
}

// ---------------------------------------------------------------------------
// MFMA GEMM, m97 2-barrier structure, BK=64 (half the barrier-drain events
// of BK=32) + T2 XOR swizzle. LDS rows are 128B -> naive frag reads would be
// 16-way bank-conflicted; swizzle makes them 2-way (free). Rule #21: LDS dest
// of global_load_lds stays LINEAR; the per-lane GLOBAL source col is
// pre-swizzled (col8 = (lane&7)^(lane>>3)), and the ds_read address applies
// the SAME involution (slot = (kk*4+quad)^(row&7)).
// T1 XCD-chunked blockIdx swizzle (grids all %8==0 -> bijective).
// RESID=true: in-place resid==out safe (same thread reads then writes).
// ---------------------------------------------------------------------------
template <typename TA, typename TO, bool RELU, bool RESID, bool QKV,
          int WAVES_M, int WAVES_N, int WM, int WN>
__global__ __launch_bounds__(256) void mfma_gemm(
    const TA* __restrict__ A, const bf16* __restrict__ Wt,
    const float* __restrict__ bias, const bf16* __restrict__ resid,
    TO* __restrict__ out, int K, int N,
    TO* __restrict__ outk, TO* __restrict__ outv,
    const float* __restrict__ biask, const float* __restrict__ biasv) {
    constexpr int BM = WAVES_M * WM * 16;
    constexpr int BN = WAVES_N * WN * 16;
    constexpr int BK = 64;
    __shared__ bf16 As[BM][BK];
    __shared__ bf16 Bs[BN][BK];

    const int tid = threadIdx.x;
    const int wid = tid >> 6, lane = tid & 63;
    const int quad = lane >> 4, l16 = lane & 15;
    const int wm = (wid / WAVES_N) * (WM * 16);
    const int wn = (wid % WAVES_N) * (WN * 16);

    // XCD-chunked swizzle (T1)
    const int nwg = gridDim.x * gridDim.y;
    const int orig = blockIdx.y * gridDim.x + blockIdx.x;
    const int chunk = nwg >> 3;
    const int swz = (orig & 7) * chunk + (orig >> 3);
    const int bx = swz % gridDim.x;
    const int by = swz / gridDim.x;

    const long m0 = (long)by * BM;
    const long n0 = (long)bx * BN;

    // staging maps (BK=64): 32 rows per pass; lane -> row l>>3, col-slot
    // swizzled (l&7)^(l>>3). LDS dest linear: base + j*4096 + wid*1024 + l*16.
    const int srow = wid * 8 + (lane >> 3);
    const int scol = ((lane & 7) ^ (lane >> 3)) * 8;

    f32x4 acc[WM][WN] = {};

    for (int k0 = 0; k0 < K; k0 += BK) {
        __syncthreads();
        if constexpr (sizeof(TA) == 4) {
#pragma unroll
            for (int j = 0; j < BM / 32; ++j) {
                const float* ap = (const float*)A + (m0 + j * 32 + srow) * (long)K + k0 + scol;
                const float4 f0 = *(const float4*)ap;
                const float4 f1 = *(const float4*)(ap + 4);
                uint4 pk;
                pk.x = pack2bf(f0.x, f0.y); pk.y = pack2bf(f0.z, f0.w);
                pk.z = pack2bf(f1.x, f1.y); pk.w = pack2bf(f1.z, f1.w);
                *(uint4*)&As[j * 32 + srow][scol] = pk;
            }
        } else {
#pragma unroll
            for (int j = 0; j < BM / 32; ++j) {
                const bf16* ap = (const bf16*)A + (m0 + j * 32 + srow) * (long)K + k0 + scol;
                gload16(ap, (bf16*)((char*)&As[0][0] + j * 4096 + wid * 1024));
            }
        }
#pragma unroll
        for (int j = 0; j < BN / 32; ++j) {
            const bf16* bp = Wt + (n0 + j * 32 + srow) * (long)K + k0 + scol;
            gload16(bp, (bf16*)((char*)&Bs[0][0] + j * 4096 + wid * 1024));
        }
        __syncthreads();

#pragma unroll
        for (int kk = 0; kk < 2; ++kk) {
            // swizzled read slot: (kk*4+quad) ^ (row&7); row&7 == l16&7 here
            const int slot = ((kk * 4 + quad) ^ (l16 & 7)) * 8;
            bfv8 af[WM], bfr[WN];
#pragma unroll
            for (int i = 0; i < WM; ++i)
                af[i] = *(const bfv8*)&As[wm + i * 16 + l16][slot];
#pragma unroll
            for (int j = 0; j < WN; ++j)
                bfr[j] = *(const bfv8*)&Bs[wn + j * 16 + l16][slot];
#pragma unroll
            for (int i = 0; i < WM; ++i)
#pragma unroll
                for (int j = 0; j < WN; ++j)
                    acc[i][j] = __builtin_amdgcn_mfma_f32_16x16x32_bf16(af[i], bfr[j], acc[i][j], 0, 0, 0);
        }
    }

#pragma unroll
    for (int i = 0; i < WM; ++i) {
#pragma unroll
        for (int r = 0; r < 4; ++r) {
            const long m = m0 + wm + i * 16 + quad * 4 + r;
#pragma unroll
            for (int j = 0; j < WN; ++j) {
                const long n = n0 + wn + j * 16 + l16;
                float val = acc[i][j][r];
                if constexpr (QKV) {
                    const int sel = (int)(n >> 10);
                    const long nn = n & 1023;
                    TO* op = sel == 0 ? out : (sel == 1 ? outk : outv);
                    const float* bp = sel == 0 ? bias : (sel == 1 ? biask : biasv);
                    store_val(op + m * 1024 + nn, val + bp[nn]);
                } else {
                    val += bias[n];
                    if constexpr (RELU) val = fmaxf(val, 0.f);
                    if constexpr (RESID) val += bf2f(resid[m * (long)N + n]);
                    store_val(out + m * (long)N + n, val);
                }
            }
        }
    }
}

// ---------------------------------------------------------------------------
// MFMA local causal attention, v3: QBLK=128 (8 waves of 16 queries, 512 thr)
// + T14 register prefetch + T5 setprio around pure-MFMA clusters + T1
// XCD-chunk swizzle (same-head query tiles share K/V -> localize per XCD L2).
// Math identical to the verified version: fixed-max softmax
// p = exp2(fma(s, 0.125*log2e, -16*log2e)); K staged [key][d]; V transposed
// [d][key]; P round-trips LDS per wave; rows padded to 72 elems. Output
// (2*attn, bf16) overwrites Q in place; race-free per-wave ownership.
// ---------------------------------------------------------------------------
__global__ __launch_bounds__(512) void attn_mfma(
    bf16* __restrict__ q, const bf16* __restrict__ k,
    const bf16* __restrict__ v) {
    constexpr int LDK = 72;
    __shared__ bf16 Ks[64][LDK];
    __shared__ bf16 Vt[64][LDK];
    __shared__ bf16 Ps[8][16][LDK];

    const int tid = threadIdx.x;
    const int wid = tid >> 6, lane = tid & 63;
    const int quad = lane >> 4, l16 = lane & 15;
    // T1 swizzle: grid = 2048 (%8==0); XCD x gets a contiguous run of 256
    // tiles = 8 consecutive heads' full query range.
    const int orig = blockIdx.x;
    const int swzb = (orig & 7) * ((int)gridDim.x >> 3) + (orig >> 3);
    const int qt = swzb & 31;          // S/128 = 32 query tiles
    const int bh = swzb >> 5;
    const int b_ = bh >> 4, h_ = bh & 15;
    const int qbase = qt * 128;
    const int wstart = qbase & ~(WIN - 1);
    const int kstart = (wstart == 0) ? 0 : wstart - WIN;
    const int ntiles = (qbase + 128 - kstart) >> 6;

    const long headoff = (long)h_ * DH;

    // Q A-frags: A[m=l16][k=quad*8+j], two k-chunks (0..31, 32..63)
    const bf16* qrow = q + ((long)b_ * S + qbase + wid * 16 + l16) * D + headoff + quad * 8;
    const bfv8 qa0 = *(const bfv8*)qrow;
    const bfv8 qa1 = *(const bfv8*)(qrow + 32);

    // staging index maps (512 threads)
    const int skey = tid >> 3;          // K: row 0..63, 8 thr/row
    const int sdp  = (tid & 7) * 8;     // K: 8-elem d group
    const int vkey = tid & 63;          // V: key (lane) -> conflict-free writes
    const int vdg  = tid >> 6;          // V: d group 0..7 (= wid)

    const bf16* kbase = k + (long)b_ * S * D + headoff;
    const bf16* vbase = v + (long)b_ * S * D + headoff;

    f32x4 o[4] = {};
    float lacc[4] = {};
    const int qp = qbase + wid * 16 + quad * 4;  // query pos of r=0

    // prefetch tile 0
    uint4 kreg = *(const uint4*)(kbase + (long)(kstart + skey) * D + sdp);
    uint4 vreg = *(const uint4*)(vbase + (long)(kstart + vkey) * D + vdg * 8);

    for (int t = 0; t < ntiles; ++t) {
        // write staged tile t to LDS (vmcnt wait inserted by compiler)
        *(uint4*)&Ks[skey][sdp] = kreg;
        {
            bf16 vv[8];
            *(uint4*)&vv[0] = vreg;
#pragma unroll
            for (int i = 0; i < 8; ++i) Vt[vdg * 8 + i][vkey] = vv[i];
        }
        __syncthreads();

        // prefetch tile t+1 (in flight across the whole compute phase)
        if (t + 1 < ntiles) {
            const int kn = kstart + (t + 1) * 64;
            kreg = *(const uint4*)(kbase + (long)(kn + skey) * D + sdp);
            vreg = *(const uint4*)(vbase + (long)(kn + vkey) * D + vdg * 8);
        }

        const int kpos0 = kstart + t * 64;

        // S = Q K^T  (4 chunks of 16 keys), then p = exp2(fma(s)) masked
#pragma unroll
        for (int c = 0; c < 4; ++c) {
            const bfv8 kb0 = *(const bfv8*)&Ks[c * 16 + l16][quad * 8];
            const bfv8 kb1 = *(const bfv8*)&Ks[c * 16 + l16][quad * 8 + 32];
            f32x4 s = {};
            __builtin_amdgcn_s_setprio(1);
            s = __builtin_amdgcn_mfma_f32_16x16x32_bf16(qa0, kb0, s, 0, 0, 0);
            s = __builtin_amdgcn_mfma_f32_16x16x32_bf16(qa1, kb1, s, 0, 0, 0);
            __builtin_amdgcn_s_setprio(0);
            const int kp = kpos0 + c * 16 + l16;
#pragma unroll
            for (int r = 0; r < 4; ++r) {
                const float p = (kp <= qp + r)
                    ? exp2f(fmaf(s[r], 0.18033688f, -23.083120f)) : 0.f;
                lacc[r] += p;
                Ps[wid][quad * 4 + r][c * 16 + l16] = __float2bfloat16(p);
            }
        }

        // O += P V   (A from Ps round-trip, B from transposed Vt)
#pragma unroll
        for (int c2 = 0; c2 < 2; ++c2) {
            const bfv8 pa = *(const bfv8*)&Ps[wid][l16][c2 * 32 + quad * 8];
            bfv8 vb[4];
#pragma unroll
            for (int dc = 0; dc < 4; ++dc)
                vb[dc] = *(const bfv8*)&Vt[dc * 16 + l16][c2 * 32 + quad * 8];
            __builtin_amdgcn_s_setprio(1);
#pragma unroll
            for (int dc = 0; dc < 4; ++dc)
                o[dc] = __builtin_amdgcn_mfma_f32_16x16x32_bf16(pa, vb[dc], o[dc], 0, 0, 0);
            __builtin_amdgcn_s_setprio(0);
        }
        __syncthreads();  // all waves done reading before next writes
    }

    // reduce l across the 16-lane key-column group (masks 1,2,4,8 stay in-group)
#pragma unroll
    for (int r = 0; r < 4; ++r) {
#pragma unroll
        for (int m = 1; m < 16; m <<= 1) lacc[r] += __shfl_xor(lacc[r], m, 64);
    }
    float inv[4];
#pragma unroll
    for (int r = 0; r < 4; ++r) inv[r] = 2.f / lacc[r];  // x2 = "attn + attn"

    bf16* orow = q + ((long)b_ * S + qp) * D + headoff;
#pragma unroll
    for (int r = 0; r < 4; ++r)
#pragma unroll
        for (int dc = 0; dc < 4; ++dc)
            orow[(long)r * D + dc * 16 + l16] = __float2bfloat16(o[dc][r] * inv[r]);
}

// ---------------------------------------------------------------------------
// LayerNorm over last dim (1024), biased var, in-place safe.
// ADD=true: normalizes (in + in2) -- fused residual add.
// ---------------------------------------------------------------------------
template <typename TI, typename TO, bool ADD>
__global__ __launch_bounds__(256) void ln_kernel(
    const TI* in, const float* __restrict__ g, const float* __restrict__ be,
    TO* out, const TI* in2) {
    __shared__ float red[4];
    const long row = blockIdx.x;
    const TI* x = in + row * D;
    const TI* x2 = ADD ? in2 + row * D : nullptr;
    const int tid = threadIdx.x;

    float v[4];
    float s = 0.f;
#pragma unroll
    for (int i = 0; i < 4; ++i) {
        v[i] = (float)x[tid + i * 256];
        if constexpr (ADD) v[i] += (float)x2[tid + i * 256];
        s += v[i];
    }
#pragma unroll
    for (int off = 32; off; off >>= 1) s += __shfl_down(s, off, 64);
    if ((tid & 63) == 0) red[tid >> 6] = s;
    __syncthreads();
    const float mu = (red[0] + red[1] + red[2] + red[3]) * (1.f / D);
    __syncthreads();

    float vs = 0.f;
#pragma unroll
    for (int i = 0; i < 4; ++i) {
        const float d0 = v[i] - mu;
        vs += d0 * d0;
    }
#pragma unroll
    for (int off = 32; off; off >>= 1) vs += __shfl_down(vs, off, 64);
    if ((tid & 63) == 0) red[tid >> 6] = vs;
    __syncthreads();
    const float inv = rsqrtf((red[0] + red[1] + red[2] + red[3]) * (1.f / D) + 1e-5f);

#pragma unroll
    for (int i = 0; i < 4; ++i) {
        const int c = tid + i * 256;
        store_val(out + row * D + c, (v[i] - mu) * inv * g[c] + be[c]);
    }
}

// ---------------------------------------------------------------------------
extern "C" void kernel_launch(void* const* d_in, const int* in_sizes, int n_in,
                              void* d_out, int out_size, void* d_ws, size_t ws_size,
                              hipStream_t stream) {
    const float* src = (const float*)d_in[0];
    const float* wq = (const float*)d_in[1];  const float* bq = (const float*)d_in[2];
    const float* wk = (const float*)d_in[3];  const float* bk = (const float*)d_in[4];
    const float* wv = (const float*)d_in[5];  const float* bv = (const float*)d_in[6];
    const float* w1 = (const float*)d_in[7];  const float* b1 = (const float*)d_in[8];
    const float* w2 = (const float*)d_in[9];  const float* b2 = (const float*)d_in[10];
    const float* g1 = (const float*)d_in[11]; const float* be1 = (const float*)d_in[12];
    const float* g2 = (const float*)d_in[13]; const float* be2 = (const float*)d_in[14];

    // Buffer liveness plan:
    //  ws  (64 MiB): qb/x/z [0,32) | phase1: wqkvb[32,38), srcb[40,56)
    //                              | phase2: w1b[32,40), w2b[40,48)
    //  d_out (64 MiB): phase1: kb[0,32), vb[32,64)  (dead after attn)
    //                  phase2: hb[0,64)  (full 8192x4096 bf16 h chunk)
    //                  finally: LN2 writes f32 y over all of d_out (hb dead).
    //  gemm2 fuses resid-add and writes z = x+ffn bf16 IN-PLACE over qb.
    char* ws = (char*)d_ws;
    bf16* qb    = (bf16*)ws;
    bf16* wqkvb = (bf16*)(ws + (32L << 20));
    bf16* srcb  = (bf16*)(ws + (40L << 20));
    bf16* w1b   = (bf16*)(ws + (32L << 20));
    bf16* w2b   = (bf16*)(ws + (40L << 20));
    char* dob   = (char*)d_out;
    bf16* kb    = (bf16*)dob;
    bf16* vb    = (bf16*)(dob + (32L << 20));
    bf16* hb    = (bf16*)dob;

    const dim3 blk(256);

    // QKV weights -> bf16
    f2b_kernel<<<dim3(512),  blk, 0, stream>>>(wq, wqkvb,            131072);
    f2b_kernel<<<dim3(512),  blk, 0, stream>>>(wk, wqkvb + (1L<<20), 131072);
    f2b_kernel<<<dim3(512),  blk, 0, stream>>>(wv, wqkvb + (2L<<20), 131072);

    // Fused QKV GEMM in 2 row-chunks: convert src chunk -> bf16, then
    // [8192,1024](bf16) x [3072,1024]^T via the global_load_lds A-path.
    for (int ch = 0; ch < NQCH; ++ch) {
        const long off = (long)ch * QCH * D;
        f2b_kernel<<<dim3(QCH * D / 8 / 256), blk, 0, stream>>>(
            src + off, srcb, QCH * D / 8);
        mfma_gemm<bf16, bf16, false, false, true, 2, 2, 4, 4>
            <<<dim3(3072 / 128, QCH / 128), blk, 0, stream>>>(
                srcb, wqkvb, bq, nullptr, qb + off, D, 3072,
                kb + off, vb + off, bk, bv);
    }

    // FFN weights -> bf16 into ws[32,48) (wqkvb/srcb dead after QKV gemms)
    f2b_kernel<<<dim3(2048), blk, 0, stream>>>(w1, w1b, 524288);
    f2b_kernel<<<dim3(2048), blk, 0, stream>>>(w2, w2b, 524288);

    // MFMA local attention: x = 2*attn (bf16) over Q buffer (512-thr wgs)
    attn_mfma<<<dim3(B * H * (S / 128)), dim3(512), 0, stream>>>(qb, kb, vb);

    // LN1 in place on qb
    ln_kernel<bf16, bf16, false><<<dim3(M_ROWS), blk, 0, stream>>>(
        qb, g1, be1, qb, nullptr);

    // FFN in 2 chunks of 8192 rows; hb = all of d_out (kb/vb dead).
    // gemm1: 2048 wg (8/CU); gemm2: 1024 wg (4/CU), z = x+ffn in-place on qb.
    for (int ch = 0; ch < NFCH; ++ch) {
        bf16* xc = qb + (long)ch * FCH * D;
        mfma_gemm<bf16, bf16, true, false, false, 2, 2, 4, 4>
            <<<dim3(4096 / 128, FCH / 128), blk, 0, stream>>>(
                xc, w1b, b1, nullptr, hb, D, 4 * D, nullptr, nullptr, nullptr, nullptr);
        mfma_gemm<bf16, bf16, false, true, false, 4, 1, 2, 4>
            <<<dim3(1024 / 64, FCH / 128), blk, 0, stream>>>(
                hb, w2b, b2, xc, xc, 4 * D, D, nullptr, nullptr, nullptr, nullptr);
    }

    // LN2 on z (bf16, in qb), write f32 into d_out (hb dead)
    ln_kernel<bf16, float, false><<<dim3(M_ROWS), blk, 0, stream>>>(
        qb, g2, be2, (float*)d_out, nullptr);
}